// Round 1
// baseline (6103.404 us; speedup 1.0000x reference)
//
#include <hip/hip_runtime.h>
#include <math.h>

#define HH 192
#define WW 192
#define HW (192*192)

// ---------------- weight transpose: w[co][ci][3][3] -> wt[ci][k][co_pad] ----------------
__global__ void transpose_w_kernel(const float* __restrict__ w, float* __restrict__ wt,
                                   int cout_real, int cout_pad, int cin) {
    int idx = blockIdx.x * 256 + threadIdx.x;
    int total = cin * 9 * cout_pad;
    if (idx >= total) return;
    int co = idx % cout_pad;
    int k  = (idx / cout_pad) % 9;
    int ic = idx / (cout_pad * 9);
    wt[idx] = (co < cout_real) ? w[((size_t)co * cin + ic) * 9 + k] : 0.f;
}

// ---------------- generic 3x3 conv, stride 1, pad 1 ----------------
// block: 256 threads = 8 co-groups x 32 px-groups. Tile 16x16 pixels, COUT_PAD = 8*CO_PER couts.
// IN_MODE: 0 = plain [N,CIN,H,W]; 1 = concat(x[N,64], ref_f[N,64]); 2 = ref_x flip-augment (CIN=12)
template<int CIN, int CHUNK, int CO_PER, bool RELU, int IN_MODE, bool SCALE>
__global__ __launch_bounds__(256, 2)
void conv3x3_kernel(const float* __restrict__ in0, const float* __restrict__ in1,
                    const float* __restrict__ wt, const float* __restrict__ bias,
                    const float* __restrict__ scale,
                    float* __restrict__ out0, float* __restrict__ out1,
                    int cout_real)
{
    constexpr int COUT_PAD = CO_PER * 8;
    constexpr int NCHUNK = CIN / CHUNK;
    __shared__ float sX[CHUNK][18][20];
    __shared__ float sW[CHUNK][9][COUT_PAD];

    const int tid = threadIdx.x;
    const int n   = blockIdx.z;
    const int ty0 = blockIdx.y * 16, tx0 = blockIdx.x * 16;
    const int co_id = tid >> 5;
    const int px_id = tid & 31;
    const int row = px_id >> 1;
    const int c8  = (px_id & 1) * 8;

    float acc[CO_PER][8];
#pragma unroll
    for (int c = 0; c < CO_PER; ++c)
#pragma unroll
        for (int p = 0; p < 8; ++p) acc[c][p] = 0.f;

    for (int cb = 0; cb < NCHUNK; ++cb) {
        // stage weights (contiguous, coalesced)
        const float* wsrc = wt + (size_t)cb * CHUNK * 9 * COUT_PAD;
        for (int e = tid; e < CHUNK * 9 * COUT_PAD; e += 256)
            ((float*)sW)[e] = wsrc[e];
        // stage input tile with halo
        for (int idx = tid; idx < CHUNK * 324; idx += 256) {
            int ic = idx / 324;
            int j  = idx - ic * 324;
            int ly = j / 18;
            int lx = j - ly * 18;
            int gy = ty0 - 1 + ly;
            int gx = tx0 - 1 + lx;
            int gc = cb * CHUNK + ic;
            float v = 0.f;
            if (gy >= 0 && gy < HH && gx >= 0 && gx < WW) {
                if constexpr (IN_MODE == 0) {
                    v = in0[((size_t)(n * CIN + gc)) * HW + gy * WW + gx];
                } else if constexpr (IN_MODE == 1) {
                    const float* src = (gc < 64) ? (in0 + ((size_t)(n * 64 + gc)) * HW)
                                                 : (in1 + ((size_t)(n * 64 + gc - 64)) * HW);
                    v = src[gy * WW + gx];
                } else {
                    int srcc = gc % 3;
                    int mode = gc / 3;
                    int ry = (mode & 1) ? (HH - 1 - gy) : gy;
                    int rx = (mode & 2) ? (WW - 1 - gx) : gx;
                    v = in0[((size_t)(n * 3 + srcc)) * HW + ry * WW + rx];
                }
                if constexpr (SCALE) v *= scale[n * CIN + gc];
            }
            sX[ic][ly][lx] = v;
        }
        __syncthreads();
        // compute
#pragma unroll
        for (int ic = 0; ic < CHUNK; ++ic) {
            float xr[3][12];
#pragma unroll
            for (int ky = 0; ky < 3; ++ky) {
                const float4* xp = (const float4*)(&sX[ic][row + ky][c8]);
                float4 a = xp[0], b = xp[1], cc = xp[2];
                xr[ky][0]=a.x;  xr[ky][1]=a.y;  xr[ky][2]=a.z;  xr[ky][3]=a.w;
                xr[ky][4]=b.x;  xr[ky][5]=b.y;  xr[ky][6]=b.z;  xr[ky][7]=b.w;
                xr[ky][8]=cc.x; xr[ky][9]=cc.y; xr[ky][10]=cc.z; xr[ky][11]=cc.w;
            }
#pragma unroll
            for (int ky = 0; ky < 3; ++ky) {
#pragma unroll
                for (int kx = 0; kx < 3; ++kx) {
                    float wv[CO_PER];
                    if constexpr ((CO_PER & 3) == 0) {
#pragma unroll
                        for (int q = 0; q < CO_PER / 4; ++q) {
                            float4 w4 = *(const float4*)(&sW[ic][ky*3+kx][co_id*CO_PER + q*4]);
                            wv[q*4+0]=w4.x; wv[q*4+1]=w4.y; wv[q*4+2]=w4.z; wv[q*4+3]=w4.w;
                        }
                    } else {
#pragma unroll
                        for (int c = 0; c < CO_PER; ++c)
                            wv[c] = sW[ic][ky*3+kx][co_id*CO_PER + c];
                    }
#pragma unroll
                    for (int p = 0; p < 8; ++p) {
                        float xv = xr[ky][kx + p];
#pragma unroll
                        for (int c = 0; c < CO_PER; ++c)
                            acc[c][p] = fmaf(xv, wv[c], acc[c][p]);
                    }
                }
            }
        }
        __syncthreads();
    }
    // epilogue
    const int gy = ty0 + row;
    const int gx = tx0 + c8;
#pragma unroll
    for (int c = 0; c < CO_PER; ++c) {
        int co_g = co_id * CO_PER + c;
        if (co_g < cout_real) {
            float bv = bias[co_g];
            float r[8];
#pragma unroll
            for (int p = 0; p < 8; ++p) {
                float v = acc[c][p] + bv;
                if (RELU) v = fmaxf(v, 0.f);
                r[p] = v;
            }
            size_t o = ((size_t)(n * cout_real + co_g)) * HW + (size_t)gy * WW + gx;
            float4* d0 = (float4*)(out0 + o);
            d0[0] = make_float4(r[0], r[1], r[2], r[3]);
            d0[1] = make_float4(r[4], r[5], r[6], r[7]);
            if (out1) {
                float4* d1 = (float4*)(out1 + o);
                d1[0] = make_float4(r[0], r[1], r[2], r[3]);
                d1[1] = make_float4(r[4], r[5], r[6], r[7]);
            }
        }
    }
}

// ---------------- global average pool: one block per (n,c) ----------------
__global__ void gap_kernel(const float* __restrict__ t, float* __restrict__ o) {
    int nc = blockIdx.x;
    const float4* p = (const float4*)(t + (size_t)nc * HW);
    float s = 0.f;
    for (int i = threadIdx.x; i < HW / 4; i += 256) {
        float4 v = p[i];
        s += (v.x + v.y) + (v.z + v.w);
    }
#pragma unroll
    for (int d = 32; d; d >>= 1) s += __shfl_down(s, d);
    __shared__ float ps[4];
    if ((threadIdx.x & 63) == 0) ps[threadIdx.x >> 6] = s;
    __syncthreads();
    if (threadIdx.x == 0) o[nc] = (ps[0] + ps[1] + ps[2] + ps[3]) * (1.f / (float)HW);
}

// ---------------- channel-attention FC: GAP[n,64] -> sigmoid scale[n,64] ----------------
__global__ void ca_fc_kernel(const float* __restrict__ g, const float* __restrict__ w1,
                             const float* __restrict__ b1, const float* __restrict__ w2,
                             const float* __restrict__ b2, float* __restrict__ s)
{
    int n = blockIdx.x;
    int c = threadIdx.x;  // 64
    __shared__ float y[64], z[4];
    y[c] = g[n * 64 + c];
    __syncthreads();
    if (c < 4) {
        float a = b1[c];
        for (int i = 0; i < 64; ++i) a = fmaf(w1[c * 64 + i], y[i], a);
        z[c] = fmaxf(a, 0.f);
    }
    __syncthreads();
    float a = b2[c];
#pragma unroll
    for (int q = 0; q < 4; ++q) a = fmaf(w2[c * 4 + q], z[q], a);
    s[n * 64 + c] = 1.f / (1.f + expf(-a));
}

// ---------------- deformable conv 3x3 (torchvision semantics) + bias + relu ----------------
__global__ __launch_bounds__(256, 2)
void dcn_kernel(const float* __restrict__ x, const float* __restrict__ off,
                const float* __restrict__ wt /*[ic][tap][co]*/, const float* __restrict__ bias,
                float* __restrict__ out)
{
    __shared__ float sW[8][9][64];
    __shared__ float sS[8][256];
    const int tid = threadIdx.x;
    const int n   = blockIdx.z;
    const int ty0 = blockIdx.y * 16, tx0 = blockIdx.x * 16;
    // gather role: one pixel per thread
    const int ggy = ty0 + (tid >> 4);
    const int ggx = tx0 + (tid & 15);
    // compute role
    const int co_id = tid >> 5;
    const int px_id = tid & 31;
    const int row = px_id >> 1;
    const int c8  = (px_id & 1) * 8;

    const float* xn = x + (size_t)n * 64 * HW;

    float acc[8][8];
#pragma unroll
    for (int c = 0; c < 8; ++c)
#pragma unroll
        for (int p = 0; p < 8; ++p) acc[c][p] = 0.f;

    for (int cb = 0; cb < 8; ++cb) {
        __syncthreads();  // protect sW from previous chunk's readers
        const float* wsrc = wt + (size_t)cb * 8 * 9 * 64;
        for (int e = tid; e < 8 * 9 * 64; e += 256) ((float*)sW)[e] = wsrc[e];

        for (int tap = 0; tap < 9; ++tap) {
            const int ti = tap / 3, tj = tap - ti * 3;
            float dy = off[((size_t)(n * 18 + 2 * tap)) * HW + ggy * WW + ggx];
            float dx = off[((size_t)(n * 18 + 2 * tap + 1)) * HW + ggy * WW + ggx];
            float py  = (float)(ggy + ti - 1) + dy;
            float pxx = (float)(ggx + tj - 1) + dx;
            float y0f = floorf(py), x0f = floorf(pxx);
            float wy1 = py - y0f, wx1 = pxx - x0f;
            float wy0 = 1.f - wy1, wx0 = 1.f - wx1;
            int y0 = (int)y0f, x0 = (int)x0f;
            int y1 = y0 + 1, x1 = x0 + 1;
            float vy0 = (y0 >= 0 && y0 < HH) ? 1.f : 0.f;
            float vy1 = (y1 >= 0 && y1 < HH) ? 1.f : 0.f;
            float vx0 = (x0 >= 0 && x0 < WW) ? 1.f : 0.f;
            float vx1 = (x1 >= 0 && x1 < WW) ? 1.f : 0.f;
            float w00 = wy0 * wx0 * vy0 * vx0, w01 = wy0 * wx1 * vy0 * vx1;
            float w10 = wy1 * wx0 * vy1 * vx0, w11 = wy1 * wx1 * vy1 * vx1;
            int yc0 = min(max(y0, 0), HH - 1), yc1 = min(max(y1, 0), HH - 1);
            int xc0 = min(max(x0, 0), WW - 1), xc1 = min(max(x1, 0), WW - 1);
            int b00 = yc0 * WW + xc0, b01 = yc0 * WW + xc1;
            int b10 = yc1 * WW + xc0, b11 = yc1 * WW + xc1;
            __syncthreads();  // previous tap consumers done before overwriting sS
#pragma unroll
            for (int ic = 0; ic < 8; ++ic) {
                const float* pl = xn + (size_t)(cb * 8 + ic) * HW;
                float v = pl[b00] * w00 + pl[b01] * w01 + pl[b10] * w10 + pl[b11] * w11;
                sS[ic][tid] = v;
            }
            __syncthreads();
#pragma unroll
            for (int ic = 0; ic < 8; ++ic) {
                float4 s0 = *(const float4*)&sS[ic][row * 16 + c8];
                float4 s1 = *(const float4*)&sS[ic][row * 16 + c8 + 4];
                float4 w0 = *(const float4*)&sW[ic][tap][co_id * 8];
                float4 w1 = *(const float4*)&sW[ic][tap][co_id * 8 + 4];
                float sv[8] = {s0.x, s0.y, s0.z, s0.w, s1.x, s1.y, s1.z, s1.w};
                float wv[8] = {w0.x, w0.y, w0.z, w0.w, w1.x, w1.y, w1.z, w1.w};
#pragma unroll
                for (int c = 0; c < 8; ++c)
#pragma unroll
                    for (int p = 0; p < 8; ++p)
                        acc[c][p] = fmaf(sv[p], wv[c], acc[c][p]);
            }
        }
    }
    // epilogue: bias + relu
    const int gy = ty0 + row, gx = tx0 + c8;
#pragma unroll
    for (int c = 0; c < 8; ++c) {
        int co_g = co_id * 8 + c;
        float bv = bias[co_g];
        float r[8];
#pragma unroll
        for (int p = 0; p < 8; ++p) r[p] = fmaxf(acc[c][p] + bv, 0.f);
        size_t o = ((size_t)(n * 64 + co_g)) * HW + (size_t)gy * WW + gx;
        float4* d0 = (float4*)(out + o);
        d0[0] = make_float4(r[0], r[1], r[2], r[3]);
        d0[1] = make_float4(r[4], r[5], r[6], r[7]);
    }
}

extern "C" void kernel_launch(void* const* d_in, const int* in_sizes, int n_in,
                              void* d_out, int out_size, void* d_ws, size_t ws_size,
                              hipStream_t stream)
{
    const float* x      = (const float*)d_in[0];
    const float* ref_x  = (const float*)d_in[1];
    const float* ref_w  = (const float*)d_in[2];
    const float* ref_b  = (const float*)d_in[3];
    const float* off_w1 = (const float*)d_in[4];
    const float* off_b1 = (const float*)d_in[5];
    const float* ca1_w1 = (const float*)d_in[6];
    const float* ca1_b1 = (const float*)d_in[7];
    const float* ca1_w2 = (const float*)d_in[8];
    const float* ca1_b2 = (const float*)d_in[9];
    const float* off_w2 = (const float*)d_in[10];
    const float* off_b2 = (const float*)d_in[11];
    const float* ca2_w1 = (const float*)d_in[12];
    const float* ca2_b1 = (const float*)d_in[13];
    const float* ca2_w2 = (const float*)d_in[14];
    const float* ca2_b2 = (const float*)d_in[15];
    const float* off_w3 = (const float*)d_in[16];
    const float* off_b3 = (const float*)d_in[17];
    const float* dcn_w  = (const float*)d_in[18];
    const float* dcn_b  = (const float*)d_in[19];
    const float* rgb_w  = (const float*)d_in[20];
    const float* rgb_b  = (const float*)d_in[21];

    float* out = (float*)d_out;
    const size_t XO  = (size_t)8 * 64 * HW;  // 18,874,368
    const size_t RGB = (size_t)8 * 3 * HW;   //    884,736
    const size_t OFF = (size_t)8 * 18 * HW;  //  5,308,416
    float* xo_out   = out;
    float* rgb_out  = out + XO;
    float* mask_out = out + XO + RGB;
    float* off_out  = out + XO + RGB + OFF;

    float* w = (float*)d_ws;
    float* bufA = w;               // ref_f, later t2
    float* bufB = w + XO;          // t1
    float* wt_ref = w + 2 * XO;            // 12*9*64  = 6912
    float* wt_1   = wt_ref + 6912;         // 128*9*64 = 73728
    float* wt_2   = wt_1 + 73728;          // 64*9*64  = 36864
    float* wt_3   = wt_2 + 36864;          // 64*9*24  = 13824
    float* wt_d   = wt_3 + 13824;          // 64*9*64  = 36864
    float* wt_r   = wt_d + 36864;          // 64*9*8   = 4608
    float* gap1   = wt_r + 4608;
    float* s1     = gap1 + 512;
    float* gap2   = s1 + 512;
    float* s2     = gap2 + 512;

    dim3 cgrid(12, 12, 8);

    transpose_w_kernel<<<27, 256, 0, stream>>>(ref_w, wt_ref, 64, 64, 12);
    transpose_w_kernel<<<288, 256, 0, stream>>>(off_w1, wt_1, 64, 64, 128);
    transpose_w_kernel<<<144, 256, 0, stream>>>(off_w2, wt_2, 64, 64, 64);
    transpose_w_kernel<<<54, 256, 0, stream>>>(off_w3, wt_3, 18, 24, 64);
    transpose_w_kernel<<<144, 256, 0, stream>>>(dcn_w, wt_d, 64, 64, 64);
    transpose_w_kernel<<<18, 256, 0, stream>>>(rgb_w, wt_r, 3, 8, 64);

    // ref branch: flip-augment 12 -> 64, relu  -> bufA (ref_f)
    conv3x3_kernel<12, 12, 8, true, 2, false><<<cgrid, 256, 0, stream>>>(
        ref_x, nullptr, wt_ref, ref_b, nullptr, bufA, nullptr, 64);
    // off conv1: concat(x, ref_f) 128 -> 64, relu  -> bufB (t1)
    conv3x3_kernel<128, 8, 8, true, 1, false><<<cgrid, 256, 0, stream>>>(
        x, bufA, wt_1, off_b1, nullptr, bufB, nullptr, 64);
    // CA1
    gap_kernel<<<512, 256, 0, stream>>>(bufB, gap1);
    ca_fc_kernel<<<8, 64, 0, stream>>>(gap1, ca1_w1, ca1_b1, ca1_w2, ca1_b2, s1);
    // off conv2: (t1 * s1) 64 -> 64, relu  -> bufA (t2)
    conv3x3_kernel<64, 8, 8, true, 0, true><<<cgrid, 256, 0, stream>>>(
        bufB, nullptr, wt_2, off_b2, s1, bufA, nullptr, 64);
    // CA2
    gap_kernel<<<512, 256, 0, stream>>>(bufA, gap2);
    ca_fc_kernel<<<8, 64, 0, stream>>>(gap2, ca2_w1, ca2_b1, ca2_w2, ca2_b2, s2);
    // off conv3: (t2 * s2) 64 -> 18, no relu  -> offset & mask (identical)
    conv3x3_kernel<64, 8, 3, false, 0, true><<<cgrid, 256, 0, stream>>>(
        bufA, nullptr, wt_3, off_b3, s2, off_out, mask_out, 18);
    // deformable conv + relu -> xo
    dcn_kernel<<<cgrid, 256, 0, stream>>>(x, off_out, wt_d, dcn_b, xo_out);
    // rgb conv: xo 64 -> 3, no relu
    conv3x3_kernel<64, 8, 1, false, 0, false><<<cgrid, 256, 0, stream>>>(
        xo_out, nullptr, wt_r, rgb_b, nullptr, rgb_out, nullptr, 3);
}

// Round 2
// 5663.566 us; speedup vs baseline: 1.0777x; 1.0777x over previous
//
#include <hip/hip_runtime.h>
#include <math.h>

#define HH 192
#define WW 192
#define HW (192*192)

// ---------------- weight transpose: w[co][ci][3][3] -> wt[ci][k][co_pad] ----------------
__global__ void transpose_w_kernel(const float* __restrict__ w, float* __restrict__ wt,
                                   int cout_real, int cout_pad, int cin) {
    int idx = blockIdx.x * 256 + threadIdx.x;
    int total = cin * 9 * cout_pad;
    if (idx >= total) return;
    int co = idx % cout_pad;
    int k  = (idx / cout_pad) % 9;
    int ic = idx / (cout_pad * 9);
    wt[idx] = (co < cout_real) ? w[((size_t)co * cin + ic) * 9 + k] : 0.f;
}

// ---------------- generic 3x3 conv, stride 1, pad 1 ----------------
// block: 512 threads = 16 co-groups x 32 px-lanes. Tile 16x16 pixels.
// CO_PER = COUT_PAD/16 couts per thread, 8 px per thread -> acc[CO_PER][8] (<=32 regs).
// IN_MODE: 0 = plain [N,CIN,H,W]; 1 = concat(x[N,64], ref_f[N,64]); 2 = ref_x flip-augment (CIN=12)
template<int CIN, int CHUNK, int COUT_PAD, bool RELU, int IN_MODE, bool SCALE>
__global__ __launch_bounds__(512, 4)
void conv3x3_kernel(const float* __restrict__ in0, const float* __restrict__ in1,
                    const float* __restrict__ wt, const float* __restrict__ bias,
                    const float* __restrict__ scale,
                    float* __restrict__ out0, float* __restrict__ out1,
                    int cout_real)
{
    constexpr int CO_PER = COUT_PAD / 16;
    constexpr int NCHUNK = CIN / CHUNK;
    __shared__ float sX[CHUNK][18][20];
    __shared__ float sW[CHUNK][9][COUT_PAD];

    const int tid = threadIdx.x;
    const int n   = blockIdx.z;
    const int ty0 = blockIdx.y * 16, tx0 = blockIdx.x * 16;
    const int co_id = tid >> 5;          // 0..15
    const int px_id = tid & 31;
    const int row = px_id >> 1;          // 0..15
    const int c8  = (px_id & 1) * 8;     // 0 or 8

    float acc[CO_PER][8];
#pragma unroll
    for (int c = 0; c < CO_PER; ++c)
#pragma unroll
        for (int p = 0; p < 8; ++p) acc[c][p] = 0.f;

    for (int cb = 0; cb < NCHUNK; ++cb) {
        // stage weights (contiguous, coalesced)
        const float* wsrc = wt + (size_t)cb * CHUNK * 9 * COUT_PAD;
        for (int e = tid; e < CHUNK * 9 * COUT_PAD; e += 512)
            ((float*)sW)[e] = wsrc[e];
        // stage input tile with halo
        for (int idx = tid; idx < CHUNK * 324; idx += 512) {
            int ic = idx / 324;
            int j  = idx - ic * 324;
            int ly = j / 18;
            int lx = j - ly * 18;
            int gy = ty0 - 1 + ly;
            int gx = tx0 - 1 + lx;
            int gc = cb * CHUNK + ic;
            float v = 0.f;
            if (gy >= 0 && gy < HH && gx >= 0 && gx < WW) {
                if constexpr (IN_MODE == 0) {
                    v = in0[((size_t)(n * CIN + gc)) * HW + gy * WW + gx];
                } else if constexpr (IN_MODE == 1) {
                    const float* src = (gc < 64) ? (in0 + ((size_t)(n * 64 + gc)) * HW)
                                                 : (in1 + ((size_t)(n * 64 + gc - 64)) * HW);
                    v = src[gy * WW + gx];
                } else {
                    int srcc = gc % 3;
                    int mode = gc / 3;
                    int ry = (mode & 1) ? (HH - 1 - gy) : gy;
                    int rx = (mode & 2) ? (WW - 1 - gx) : gx;
                    v = in0[((size_t)(n * 3 + srcc)) * HW + ry * WW + rx];
                }
                if constexpr (SCALE) v *= scale[n * CIN + gc];
            }
            sX[ic][ly][lx] = v;
        }
        __syncthreads();
        // compute: per (ic,ky) cache 12 input pixels, then 3 kx taps
#pragma unroll
        for (int ic = 0; ic < CHUNK; ++ic) {
#pragma unroll
            for (int ky = 0; ky < 3; ++ky) {
                float xr[12];
                {
                    const float4* xp = (const float4*)(&sX[ic][row + ky][c8]);
                    float4 a = xp[0], b = xp[1], cc = xp[2];
                    xr[0]=a.x;  xr[1]=a.y;  xr[2]=a.z;  xr[3]=a.w;
                    xr[4]=b.x;  xr[5]=b.y;  xr[6]=b.z;  xr[7]=b.w;
                    xr[8]=cc.x; xr[9]=cc.y; xr[10]=cc.z; xr[11]=cc.w;
                }
#pragma unroll
                for (int kx = 0; kx < 3; ++kx) {
                    float wv[CO_PER];
                    if constexpr ((CO_PER & 3) == 0) {
#pragma unroll
                        for (int q = 0; q < CO_PER / 4; ++q) {
                            float4 w4 = *(const float4*)(&sW[ic][ky*3+kx][co_id*CO_PER + q*4]);
                            wv[q*4+0]=w4.x; wv[q*4+1]=w4.y; wv[q*4+2]=w4.z; wv[q*4+3]=w4.w;
                        }
                    } else {
#pragma unroll
                        for (int c = 0; c < CO_PER; ++c)
                            wv[c] = sW[ic][ky*3+kx][co_id*CO_PER + c];
                    }
#pragma unroll
                    for (int p = 0; p < 8; ++p) {
                        float xv = xr[kx + p];
#pragma unroll
                        for (int c = 0; c < CO_PER; ++c)
                            acc[c][p] = fmaf(xv, wv[c], acc[c][p]);
                    }
                }
            }
        }
        __syncthreads();
    }
    // epilogue
    const int gy = ty0 + row;
    const int gx = tx0 + c8;
#pragma unroll
    for (int c = 0; c < CO_PER; ++c) {
        int co_g = co_id * CO_PER + c;
        if (co_g < cout_real) {
            float bv = bias[co_g];
            float r[8];
#pragma unroll
            for (int p = 0; p < 8; ++p) {
                float v = acc[c][p] + bv;
                if (RELU) v = fmaxf(v, 0.f);
                r[p] = v;
            }
            size_t o = ((size_t)(n * cout_real + co_g)) * HW + (size_t)gy * WW + gx;
            float4* d0 = (float4*)(out0 + o);
            d0[0] = make_float4(r[0], r[1], r[2], r[3]);
            d0[1] = make_float4(r[4], r[5], r[6], r[7]);
            if (out1) {
                float4* d1 = (float4*)(out1 + o);
                d1[0] = make_float4(r[0], r[1], r[2], r[3]);
                d1[1] = make_float4(r[4], r[5], r[6], r[7]);
            }
        }
    }
}

// ---------------- global average pool: one block per (n,c) ----------------
__global__ void gap_kernel(const float* __restrict__ t, float* __restrict__ o) {
    int nc = blockIdx.x;
    const float4* p = (const float4*)(t + (size_t)nc * HW);
    float s = 0.f;
    for (int i = threadIdx.x; i < HW / 4; i += 256) {
        float4 v = p[i];
        s += (v.x + v.y) + (v.z + v.w);
    }
#pragma unroll
    for (int d = 32; d; d >>= 1) s += __shfl_down(s, d);
    __shared__ float ps[4];
    if ((threadIdx.x & 63) == 0) ps[threadIdx.x >> 6] = s;
    __syncthreads();
    if (threadIdx.x == 0) o[nc] = (ps[0] + ps[1] + ps[2] + ps[3]) * (1.f / (float)HW);
}

// ---------------- channel-attention FC: GAP[n,64] -> sigmoid scale[n,64] ----------------
__global__ void ca_fc_kernel(const float* __restrict__ g, const float* __restrict__ w1,
                             const float* __restrict__ b1, const float* __restrict__ w2,
                             const float* __restrict__ b2, float* __restrict__ s)
{
    int n = blockIdx.x;
    int c = threadIdx.x;  // 64
    __shared__ float y[64], z[4];
    y[c] = g[n * 64 + c];
    __syncthreads();
    if (c < 4) {
        float a = b1[c];
        for (int i = 0; i < 64; ++i) a = fmaf(w1[c * 64 + i], y[i], a);
        z[c] = fmaxf(a, 0.f);
    }
    __syncthreads();
    float a = b2[c];
#pragma unroll
    for (int q = 0; q < 4; ++q) a = fmaf(w2[c * 4 + q], z[q], a);
    s[n * 64 + c] = 1.f / (1.f + expf(-a));
}

// ---------------- deformable conv 3x3 (torchvision semantics) + bias + relu ----------------
__global__ __launch_bounds__(256, 2)
void dcn_kernel(const float* __restrict__ x, const float* __restrict__ off,
                const float* __restrict__ wt /*[ic][tap][co]*/, const float* __restrict__ bias,
                float* __restrict__ out)
{
    __shared__ float sW[8][9][64];
    __shared__ float sS[8][256];
    const int tid = threadIdx.x;
    const int n   = blockIdx.z;
    const int ty0 = blockIdx.y * 16, tx0 = blockIdx.x * 16;
    // gather role: one pixel per thread
    const int ggy = ty0 + (tid >> 4);
    const int ggx = tx0 + (tid & 15);
    // compute role
    const int co_id = tid >> 5;
    const int px_id = tid & 31;
    const int row = px_id >> 1;
    const int c8  = (px_id & 1) * 8;

    const float* xn = x + (size_t)n * 64 * HW;

    float acc[8][8];
#pragma unroll
    for (int c = 0; c < 8; ++c)
#pragma unroll
        for (int p = 0; p < 8; ++p) acc[c][p] = 0.f;

    for (int cb = 0; cb < 8; ++cb) {
        __syncthreads();  // protect sW from previous chunk's readers
        const float* wsrc = wt + (size_t)cb * 8 * 9 * 64;
        for (int e = tid; e < 8 * 9 * 64; e += 256) ((float*)sW)[e] = wsrc[e];

        for (int tap = 0; tap < 9; ++tap) {
            const int ti = tap / 3, tj = tap - ti * 3;
            float dy = off[((size_t)(n * 18 + 2 * tap)) * HW + ggy * WW + ggx];
            float dx = off[((size_t)(n * 18 + 2 * tap + 1)) * HW + ggy * WW + ggx];
            float py  = (float)(ggy + ti - 1) + dy;
            float pxx = (float)(ggx + tj - 1) + dx;
            float y0f = floorf(py), x0f = floorf(pxx);
            float wy1 = py - y0f, wx1 = pxx - x0f;
            float wy0 = 1.f - wy1, wx0 = 1.f - wx1;
            int y0 = (int)y0f, x0 = (int)x0f;
            int y1 = y0 + 1, x1 = x0 + 1;
            float vy0 = (y0 >= 0 && y0 < HH) ? 1.f : 0.f;
            float vy1 = (y1 >= 0 && y1 < HH) ? 1.f : 0.f;
            float vx0 = (x0 >= 0 && x0 < WW) ? 1.f : 0.f;
            float vx1 = (x1 >= 0 && x1 < WW) ? 1.f : 0.f;
            float w00 = wy0 * wx0 * vy0 * vx0, w01 = wy0 * wx1 * vy0 * vx1;
            float w10 = wy1 * wx0 * vy1 * vx0, w11 = wy1 * wx1 * vy1 * vx1;
            int yc0 = min(max(y0, 0), HH - 1), yc1 = min(max(y1, 0), HH - 1);
            int xc0 = min(max(x0, 0), WW - 1), xc1 = min(max(x1, 0), WW - 1);
            int b00 = yc0 * WW + xc0, b01 = yc0 * WW + xc1;
            int b10 = yc1 * WW + xc0, b11 = yc1 * WW + xc1;
            __syncthreads();  // previous tap consumers done before overwriting sS
#pragma unroll
            for (int ic = 0; ic < 8; ++ic) {
                const float* pl = xn + (size_t)(cb * 8 + ic) * HW;
                float v = pl[b00] * w00 + pl[b01] * w01 + pl[b10] * w10 + pl[b11] * w11;
                sS[ic][tid] = v;
            }
            __syncthreads();
#pragma unroll
            for (int ic = 0; ic < 8; ++ic) {
                float4 s0 = *(const float4*)&sS[ic][row * 16 + c8];
                float4 s1 = *(const float4*)&sS[ic][row * 16 + c8 + 4];
                float4 w0 = *(const float4*)&sW[ic][tap][co_id * 8];
                float4 w1 = *(const float4*)&sW[ic][tap][co_id * 8 + 4];
                float sv[8] = {s0.x, s0.y, s0.z, s0.w, s1.x, s1.y, s1.z, s1.w};
                float wv[8] = {w0.x, w0.y, w0.z, w0.w, w1.x, w1.y, w1.z, w1.w};
#pragma unroll
                for (int c = 0; c < 8; ++c)
#pragma unroll
                    for (int p = 0; p < 8; ++p)
                        acc[c][p] = fmaf(sv[p], wv[c], acc[c][p]);
            }
        }
    }
    // epilogue: bias + relu
    const int gy = ty0 + row, gx = tx0 + c8;
#pragma unroll
    for (int c = 0; c < 8; ++c) {
        int co_g = co_id * 8 + c;
        float bv = bias[co_g];
        float r[8];
#pragma unroll
        for (int p = 0; p < 8; ++p) r[p] = fmaxf(acc[c][p] + bv, 0.f);
        size_t o = ((size_t)(n * 64 + co_g)) * HW + (size_t)gy * WW + gx;
        float4* d0 = (float4*)(out + o);
        d0[0] = make_float4(r[0], r[1], r[2], r[3]);
        d0[1] = make_float4(r[4], r[5], r[6], r[7]);
    }
}

extern "C" void kernel_launch(void* const* d_in, const int* in_sizes, int n_in,
                              void* d_out, int out_size, void* d_ws, size_t ws_size,
                              hipStream_t stream)
{
    const float* x      = (const float*)d_in[0];
    const float* ref_x  = (const float*)d_in[1];
    const float* ref_w  = (const float*)d_in[2];
    const float* ref_b  = (const float*)d_in[3];
    const float* off_w1 = (const float*)d_in[4];
    const float* off_b1 = (const float*)d_in[5];
    const float* ca1_w1 = (const float*)d_in[6];
    const float* ca1_b1 = (const float*)d_in[7];
    const float* ca1_w2 = (const float*)d_in[8];
    const float* ca1_b2 = (const float*)d_in[9];
    const float* off_w2 = (const float*)d_in[10];
    const float* off_b2 = (const float*)d_in[11];
    const float* ca2_w1 = (const float*)d_in[12];
    const float* ca2_b1 = (const float*)d_in[13];
    const float* ca2_w2 = (const float*)d_in[14];
    const float* ca2_b2 = (const float*)d_in[15];
    const float* off_w3 = (const float*)d_in[16];
    const float* off_b3 = (const float*)d_in[17];
    const float* dcn_w  = (const float*)d_in[18];
    const float* dcn_b  = (const float*)d_in[19];
    const float* rgb_w  = (const float*)d_in[20];
    const float* rgb_b  = (const float*)d_in[21];

    float* out = (float*)d_out;
    const size_t XO  = (size_t)8 * 64 * HW;  // 18,874,368
    const size_t RGB = (size_t)8 * 3 * HW;   //    884,736
    const size_t OFF = (size_t)8 * 18 * HW;  //  5,308,416
    float* xo_out   = out;
    float* rgb_out  = out + XO;
    float* mask_out = out + XO + RGB;
    float* off_out  = out + XO + RGB + OFF;

    float* w = (float*)d_ws;
    float* bufA = w;               // ref_f, later t2
    float* bufB = w + XO;          // t1
    float* wt_ref = w + 2 * XO;            // 12*9*64  = 6912
    float* wt_1   = wt_ref + 6912;         // 128*9*64 = 73728
    float* wt_2   = wt_1 + 73728;          // 64*9*64  = 36864
    float* wt_3   = wt_2 + 36864;          // 64*9*32  = 18432
    float* wt_d   = wt_3 + 18432;          // 64*9*64  = 36864
    float* wt_r   = wt_d + 36864;          // 64*9*16  = 9216
    float* gap1   = wt_r + 9216;
    float* s1     = gap1 + 512;
    float* gap2   = s1 + 512;
    float* s2     = gap2 + 512;

    dim3 cgrid(12, 12, 8);

    transpose_w_kernel<<<27, 256, 0, stream>>>(ref_w, wt_ref, 64, 64, 12);
    transpose_w_kernel<<<288, 256, 0, stream>>>(off_w1, wt_1, 64, 64, 128);
    transpose_w_kernel<<<144, 256, 0, stream>>>(off_w2, wt_2, 64, 64, 64);
    transpose_w_kernel<<<72, 256, 0, stream>>>(off_w3, wt_3, 18, 32, 64);
    transpose_w_kernel<<<144, 256, 0, stream>>>(dcn_w, wt_d, 64, 64, 64);
    transpose_w_kernel<<<36, 256, 0, stream>>>(rgb_w, wt_r, 3, 16, 64);

    // ref branch: flip-augment 12 -> 64, relu  -> bufA (ref_f)
    conv3x3_kernel<12, 12, 64, true, 2, false><<<cgrid, 512, 0, stream>>>(
        ref_x, nullptr, wt_ref, ref_b, nullptr, bufA, nullptr, 64);
    // off conv1: concat(x, ref_f) 128 -> 64, relu  -> bufB (t1)
    conv3x3_kernel<128, 8, 64, true, 1, false><<<cgrid, 512, 0, stream>>>(
        x, bufA, wt_1, off_b1, nullptr, bufB, nullptr, 64);
    // CA1
    gap_kernel<<<512, 256, 0, stream>>>(bufB, gap1);
    ca_fc_kernel<<<8, 64, 0, stream>>>(gap1, ca1_w1, ca1_b1, ca1_w2, ca1_b2, s1);
    // off conv2: (t1 * s1) 64 -> 64, relu  -> bufA (t2)
    conv3x3_kernel<64, 8, 64, true, 0, true><<<cgrid, 512, 0, stream>>>(
        bufB, nullptr, wt_2, off_b2, s1, bufA, nullptr, 64);
    // CA2
    gap_kernel<<<512, 256, 0, stream>>>(bufA, gap2);
    ca_fc_kernel<<<8, 64, 0, stream>>>(gap2, ca2_w1, ca2_b1, ca2_w2, ca2_b2, s2);
    // off conv3: (t2 * s2) 64 -> 18, no relu  -> offset & mask (identical)
    conv3x3_kernel<64, 8, 32, false, 0, true><<<cgrid, 512, 0, stream>>>(
        bufA, nullptr, wt_3, off_b3, s2, off_out, mask_out, 18);
    // deformable conv + relu -> xo
    dcn_kernel<<<cgrid, 256, 0, stream>>>(x, off_out, wt_d, dcn_b, xo_out);
    // rgb conv: xo 64 -> 3, no relu
    conv3x3_kernel<64, 8, 16, false, 0, false><<<cgrid, 512, 0, stream>>>(
        xo_out, nullptr, wt_r, rgb_b, nullptr, rgb_out, nullptr, 3);
}

// Round 3
// 1908.326 us; speedup vs baseline: 3.1983x; 2.9678x over previous
//
#include <hip/hip_runtime.h>
#include <math.h>

#define HH 192
#define WW 192
#define HW (192*192)

// ---------------- weight transpose: w[co][ci][3][3] -> wt[ci][k][co_pad] ----------------
__global__ void k_wt(const float* __restrict__ w, float* __restrict__ wt,
                     int cout_real, int cout_pad, int cin) {
    int idx = blockIdx.x * 256 + threadIdx.x;
    int total = cin * 9 * cout_pad;
    if (idx >= total) return;
    int co = idx % cout_pad;
    int k  = (idx / cout_pad) % 9;
    int ic = idx / (cout_pad * 9);
    wt[idx] = (co < cout_real) ? w[((size_t)co * cin + ic) * 9 + k] : 0.f;
}

// ---------------- generic 3x3 conv body, stride 1, pad 1 ----------------
// 512 threads = 16 co-groups x 32 px-lanes; 16x16 pixel tile; acc[CO_PER][8].
// T14 async-stage: prefetch chunk cb+1 into registers during compute of cb.
// IN_MODE: 0 plain; 1 concat(x, ref_f); 2 ref_x 4-fold flip-augment.
template<int CIN, int CHUNK, int COUT_PAD, bool RELU, int IN_MODE, bool SCALE>
__device__ __forceinline__
void conv3x3_body(const float* __restrict__ in0, const float* __restrict__ in1,
                  const float* __restrict__ wt, const float* __restrict__ bias,
                  const float* __restrict__ scale,
                  float* __restrict__ out0, float* __restrict__ out1,
                  int cout_real)
{
    constexpr int CO_PER = COUT_PAD / 16;
    constexpr int NCHUNK = CIN / CHUNK;
    constexpr int NIN = CHUNK * 324;          // 18x18 halo tile per channel
    constexpr int NW  = CHUNK * 9 * COUT_PAD;
    constexpr int CNT_IN = (NIN + 511) / 512;
    constexpr int CNT_W  = (NW  + 511) / 512;

    __shared__ float sX[CHUNK][18][20];
    __shared__ float sW[CHUNK][9][COUT_PAD];

    const int tid = threadIdx.x;
    const int n   = blockIdx.z;
    const int ty0 = blockIdx.y * 16, tx0 = blockIdx.x * 16;
    const int co_id = tid >> 5;          // 0..15
    const int px_id = tid & 31;
    const int row = px_id >> 1;          // 0..15
    const int c8  = (px_id & 1) * 8;     // 0 or 8

    float rIn[CNT_IN], rW[CNT_W];

    auto prefetch = [&](int cb) {
        const float* wsrc = wt + (size_t)cb * NW;
#pragma unroll
        for (int k = 0; k < CNT_W; ++k) {
            int e = tid + k * 512;
            rW[k] = (e < NW) ? wsrc[e] : 0.f;
        }
#pragma unroll
        for (int k = 0; k < CNT_IN; ++k) {
            int idx = tid + k * 512;
            float v = 0.f;
            if (idx < NIN) {
                int ic = idx / 324;
                int j  = idx - ic * 324;
                int ly = j / 18;
                int lx = j - ly * 18;
                int gy = ty0 - 1 + ly;
                int gx = tx0 - 1 + lx;
                int gc = cb * CHUNK + ic;
                if (gy >= 0 && gy < HH && gx >= 0 && gx < WW) {
                    if constexpr (IN_MODE == 0) {
                        v = in0[((size_t)(n * CIN + gc)) * HW + gy * WW + gx];
                    } else if constexpr (IN_MODE == 1) {
                        const float* src = (gc < 64) ? (in0 + ((size_t)(n * 64 + gc)) * HW)
                                                     : (in1 + ((size_t)(n * 64 + gc - 64)) * HW);
                        v = src[gy * WW + gx];
                    } else {
                        int srcc = gc % 3;
                        int mode = gc / 3;
                        int ry = (mode & 1) ? (HH - 1 - gy) : gy;
                        int rx = (mode & 2) ? (WW - 1 - gx) : gx;
                        v = in0[((size_t)(n * 3 + srcc)) * HW + ry * WW + rx];
                    }
                    if constexpr (SCALE) v *= scale[n * CIN + gc];
                }
            }
            rIn[k] = v;
        }
    };

    auto store_lds = [&]() {
#pragma unroll
        for (int k = 0; k < CNT_W; ++k) {
            int e = tid + k * 512;
            if (e < NW) ((float*)sW)[e] = rW[k];
        }
#pragma unroll
        for (int k = 0; k < CNT_IN; ++k) {
            int idx = tid + k * 512;
            if (idx < NIN) {
                int ic = idx / 324;
                int j  = idx - ic * 324;
                int ly = j / 18;
                int lx = j - ly * 18;
                sX[ic][ly][lx] = rIn[k];
            }
        }
    };

    float acc[CO_PER][8];
#pragma unroll
    for (int c = 0; c < CO_PER; ++c)
#pragma unroll
        for (int p = 0; p < 8; ++p) acc[c][p] = 0.f;

    prefetch(0);
    for (int cb = 0; cb < NCHUNK; ++cb) {
        __syncthreads();   // previous chunk's LDS fully consumed
        store_lds();
        __syncthreads();   // LDS ready
        if (cb + 1 < NCHUNK) prefetch(cb + 1);   // loads in flight under compute

#pragma unroll
        for (int ic = 0; ic < CHUNK; ++ic) {
#pragma unroll
            for (int ky = 0; ky < 3; ++ky) {
                float xr[12];
                {
                    const float4* xp = (const float4*)(&sX[ic][row + ky][c8]);
                    float4 a = xp[0], b = xp[1], cc = xp[2];
                    xr[0]=a.x;  xr[1]=a.y;  xr[2]=a.z;  xr[3]=a.w;
                    xr[4]=b.x;  xr[5]=b.y;  xr[6]=b.z;  xr[7]=b.w;
                    xr[8]=cc.x; xr[9]=cc.y; xr[10]=cc.z; xr[11]=cc.w;
                }
#pragma unroll
                for (int kx = 0; kx < 3; ++kx) {
                    float wv[CO_PER];
                    if constexpr ((CO_PER & 3) == 0) {
#pragma unroll
                        for (int q = 0; q < CO_PER / 4; ++q) {
                            float4 w4 = *(const float4*)(&sW[ic][ky*3+kx][co_id*CO_PER + q*4]);
                            wv[q*4+0]=w4.x; wv[q*4+1]=w4.y; wv[q*4+2]=w4.z; wv[q*4+3]=w4.w;
                        }
                    } else {
#pragma unroll
                        for (int c = 0; c < CO_PER; ++c)
                            wv[c] = sW[ic][ky*3+kx][co_id*CO_PER + c];
                    }
#pragma unroll
                    for (int p = 0; p < 8; ++p) {
                        float xv = xr[kx + p];
#pragma unroll
                        for (int c = 0; c < CO_PER; ++c)
                            acc[c][p] = fmaf(xv, wv[c], acc[c][p]);
                    }
                }
            }
        }
    }

    const int gy = ty0 + row;
    const int gx = tx0 + c8;
#pragma unroll
    for (int c = 0; c < CO_PER; ++c) {
        int co_g = co_id * CO_PER + c;
        if (co_g < cout_real) {
            float bv = bias[co_g];
            float r[8];
#pragma unroll
            for (int p = 0; p < 8; ++p) {
                float v = acc[c][p] + bv;
                if (RELU) v = fmaxf(v, 0.f);
                r[p] = v;
            }
            size_t o = ((size_t)(n * cout_real + co_g)) * HW + (size_t)gy * WW + gx;
            float4* d0 = (float4*)(out0 + o);
            d0[0] = make_float4(r[0], r[1], r[2], r[3]);
            d0[1] = make_float4(r[4], r[5], r[6], r[7]);
            if (out1) {
                float4* d1 = (float4*)(out1 + o);
                d1[0] = make_float4(r[0], r[1], r[2], r[3]);
                d1[1] = make_float4(r[4], r[5], r[6], r[7]);
            }
        }
    }
}

// -------- uniquely-named conv kernels (profiler disambiguation) --------
__global__ __launch_bounds__(512, 4)
void k_conv_ref(const float* __restrict__ in0, const float* __restrict__ wt,
                const float* __restrict__ bias, float* __restrict__ out0) {
    conv3x3_body<12, 6, 64, true, 2, false>(in0, nullptr, wt, bias, nullptr, out0, nullptr, 64);
}
__global__ __launch_bounds__(512, 4)
void k_conv_off1(const float* __restrict__ in0, const float* __restrict__ in1,
                 const float* __restrict__ wt, const float* __restrict__ bias,
                 float* __restrict__ out0) {
    conv3x3_body<128, 8, 64, true, 1, false>(in0, in1, wt, bias, nullptr, out0, nullptr, 64);
}
__global__ __launch_bounds__(512, 4)
void k_conv_off2(const float* __restrict__ in0, const float* __restrict__ wt,
                 const float* __restrict__ bias, const float* __restrict__ scale,
                 float* __restrict__ out0) {
    conv3x3_body<64, 8, 64, true, 0, true>(in0, nullptr, wt, bias, scale, out0, nullptr, 64);
}
__global__ __launch_bounds__(512, 4)
void k_conv_off3(const float* __restrict__ in0, const float* __restrict__ wt,
                 const float* __restrict__ bias, const float* __restrict__ scale,
                 float* __restrict__ out0, float* __restrict__ out1) {
    conv3x3_body<64, 8, 32, false, 0, true>(in0, nullptr, wt, bias, scale, out0, out1, 18);
}
__global__ __launch_bounds__(512, 4)
void k_conv_rgb(const float* __restrict__ in0, const float* __restrict__ wt,
                const float* __restrict__ bias, float* __restrict__ out0) {
    conv3x3_body<64, 8, 16, false, 0, false>(in0, nullptr, wt, bias, nullptr, out0, nullptr, 3);
}

// ---------------- global average pool ----------------
__global__ void k_gap(const float* __restrict__ t, float* __restrict__ o) {
    int nc = blockIdx.x;
    const float4* p = (const float4*)(t + (size_t)nc * HW);
    float s = 0.f;
    for (int i = threadIdx.x; i < HW / 4; i += 256) {
        float4 v = p[i];
        s += (v.x + v.y) + (v.z + v.w);
    }
#pragma unroll
    for (int d = 32; d; d >>= 1) s += __shfl_down(s, d);
    __shared__ float ps[4];
    if ((threadIdx.x & 63) == 0) ps[threadIdx.x >> 6] = s;
    __syncthreads();
    if (threadIdx.x == 0) o[nc] = (ps[0] + ps[1] + ps[2] + ps[3]) * (1.f / (float)HW);
}

// ---------------- channel-attention FC ----------------
__global__ void k_cafc(const float* __restrict__ g, const float* __restrict__ w1,
                       const float* __restrict__ b1, const float* __restrict__ w2,
                       const float* __restrict__ b2, float* __restrict__ s)
{
    int n = blockIdx.x;
    int c = threadIdx.x;  // 64
    __shared__ float y[64], z[4];
    y[c] = g[n * 64 + c];
    __syncthreads();
    if (c < 4) {
        float a = b1[c];
        for (int i = 0; i < 64; ++i) a = fmaf(w1[c * 64 + i], y[i], a);
        z[c] = fmaxf(a, 0.f);
    }
    __syncthreads();
    float a = b2[c];
#pragma unroll
    for (int q = 0; q < 4; ++q) a = fmaf(w2[c * 4 + q], z[q], a);
    s[n * 64 + c] = 1.f / (1.f + expf(-a));
}

// ---------------- deformable conv 3x3 + bias + relu ----------------
__global__ __launch_bounds__(256, 2)
void k_dcn(const float* __restrict__ x, const float* __restrict__ off,
           const float* __restrict__ wt /*[ic][tap][co]*/, const float* __restrict__ bias,
           float* __restrict__ out)
{
    __shared__ float sW[8][9][64];
    __shared__ float sS[2][8][256];
    const int tid = threadIdx.x;
    const int n   = blockIdx.z;
    const int ty0 = blockIdx.y * 16, tx0 = blockIdx.x * 16;
    const int ggy = ty0 + (tid >> 4);
    const int ggx = tx0 + (tid & 15);
    const int co_id = tid >> 5;
    const int px_id = tid & 31;
    const int row = px_id >> 1;
    const int c8  = (px_id & 1) * 8;

    const float* xn = x + (size_t)n * 64 * HW;

    // hoist offsets + sampling coords (registers, statically indexed via unroll)
    float spy[9], spx[9];
#pragma unroll
    for (int tap = 0; tap < 9; ++tap) {
        int ti = tap / 3, tj = tap - ti * 3;
        float dy = off[((size_t)(n * 18 + 2 * tap)) * HW + ggy * WW + ggx];
        float dx = off[((size_t)(n * 18 + 2 * tap + 1)) * HW + ggy * WW + ggx];
        spy[tap] = (float)(ggy + ti - 1) + dy;
        spx[tap] = (float)(ggx + tj - 1) + dx;
    }

    float acc[8][8];
#pragma unroll
    for (int c = 0; c < 8; ++c)
#pragma unroll
        for (int p = 0; p < 8; ++p) acc[c][p] = 0.f;

    int bufsel = 0;
    for (int cb = 0; cb < 8; ++cb) {
        __syncthreads();  // prev chunk's sW readers done
        const float* wsrc = wt + (size_t)cb * 8 * 9 * 64;
        for (int e = tid; e < 8 * 9 * 64; e += 256) ((float*)sW)[e] = wsrc[e];
        __syncthreads();

#pragma unroll
        for (int tap = 0; tap < 9; ++tap) {
            float py  = spy[tap];
            float pxx = spx[tap];
            float y0f = floorf(py), x0f = floorf(pxx);
            float wy1 = py - y0f, wx1 = pxx - x0f;
            float wy0 = 1.f - wy1, wx0 = 1.f - wx1;
            int y0 = (int)y0f, x0 = (int)x0f;
            int y1 = y0 + 1, x1 = x0 + 1;
            float vy0 = (y0 >= 0 && y0 < HH) ? 1.f : 0.f;
            float vy1 = (y1 >= 0 && y1 < HH) ? 1.f : 0.f;
            float vx0 = (x0 >= 0 && x0 < WW) ? 1.f : 0.f;
            float vx1 = (x1 >= 0 && x1 < WW) ? 1.f : 0.f;
            float w00 = wy0 * wx0 * vy0 * vx0, w01 = wy0 * wx1 * vy0 * vx1;
            float w10 = wy1 * wx0 * vy1 * vx0, w11 = wy1 * wx1 * vy1 * vx1;
            int yc0 = min(max(y0, 0), HH - 1), yc1 = min(max(y1, 0), HH - 1);
            int xc0 = min(max(x0, 0), WW - 1), xc1 = min(max(x1, 0), WW - 1);
            int b00 = yc0 * WW + xc0, b01 = yc0 * WW + xc1;
            int b10 = yc1 * WW + xc0, b11 = yc1 * WW + xc1;

#pragma unroll
            for (int ic = 0; ic < 8; ++ic) {
                const float* pl = xn + (size_t)(cb * 8 + ic) * HW;
                sS[bufsel][ic][tid] = pl[b00] * w00 + pl[b01] * w01
                                    + pl[b10] * w10 + pl[b11] * w11;
            }
            __syncthreads();  // one barrier per tap (double-buffered sS)
#pragma unroll
            for (int ic = 0; ic < 8; ++ic) {
                float4 s0 = *(const float4*)&sS[bufsel][ic][row * 16 + c8];
                float4 s1 = *(const float4*)&sS[bufsel][ic][row * 16 + c8 + 4];
                float4 w0 = *(const float4*)&sW[ic][tap][co_id * 8];
                float4 w1 = *(const float4*)&sW[ic][tap][co_id * 8 + 4];
                float sv[8] = {s0.x, s0.y, s0.z, s0.w, s1.x, s1.y, s1.z, s1.w};
                float wv[8] = {w0.x, w0.y, w0.z, w0.w, w1.x, w1.y, w1.z, w1.w};
#pragma unroll
                for (int c = 0; c < 8; ++c)
#pragma unroll
                    for (int p = 0; p < 8; ++p)
                        acc[c][p] = fmaf(sv[p], wv[c], acc[c][p]);
            }
            bufsel ^= 1;
        }
    }

    const int gy = ty0 + row, gx = tx0 + c8;
#pragma unroll
    for (int c = 0; c < 8; ++c) {
        int co_g = co_id * 8 + c;
        float bv = bias[co_g];
        float r[8];
#pragma unroll
        for (int p = 0; p < 8; ++p) r[p] = fmaxf(acc[c][p] + bv, 0.f);
        size_t o = ((size_t)(n * 64 + co_g)) * HW + (size_t)gy * WW + gx;
        float4* d0 = (float4*)(out + o);
        d0[0] = make_float4(r[0], r[1], r[2], r[3]);
        d0[1] = make_float4(r[4], r[5], r[6], r[7]);
    }
}

extern "C" void kernel_launch(void* const* d_in, const int* in_sizes, int n_in,
                              void* d_out, int out_size, void* d_ws, size_t ws_size,
                              hipStream_t stream)
{
    const float* x      = (const float*)d_in[0];
    const float* ref_x  = (const float*)d_in[1];
    const float* ref_w  = (const float*)d_in[2];
    const float* ref_b  = (const float*)d_in[3];
    const float* off_w1 = (const float*)d_in[4];
    const float* off_b1 = (const float*)d_in[5];
    const float* ca1_w1 = (const float*)d_in[6];
    const float* ca1_b1 = (const float*)d_in[7];
    const float* ca1_w2 = (const float*)d_in[8];
    const float* ca1_b2 = (const float*)d_in[9];
    const float* off_w2 = (const float*)d_in[10];
    const float* off_b2 = (const float*)d_in[11];
    const float* ca2_w1 = (const float*)d_in[12];
    const float* ca2_b1 = (const float*)d_in[13];
    const float* ca2_w2 = (const float*)d_in[14];
    const float* ca2_b2 = (const float*)d_in[15];
    const float* off_w3 = (const float*)d_in[16];
    const float* off_b3 = (const float*)d_in[17];
    const float* dcn_w  = (const float*)d_in[18];
    const float* dcn_b  = (const float*)d_in[19];
    const float* rgb_w  = (const float*)d_in[20];
    const float* rgb_b  = (const float*)d_in[21];

    float* out = (float*)d_out;
    const size_t XO  = (size_t)8 * 64 * HW;
    const size_t RGB = (size_t)8 * 3 * HW;
    const size_t OFF = (size_t)8 * 18 * HW;
    float* xo_out   = out;
    float* rgb_out  = out + XO;
    float* mask_out = out + XO + RGB;
    float* off_out  = out + XO + RGB + OFF;

    float* w = (float*)d_ws;
    float* bufA = w;               // ref_f, later t2
    float* bufB = w + XO;          // t1
    float* wt_ref = w + 2 * XO;            // 12*9*64  = 6912
    float* wt_1   = wt_ref + 6912;         // 128*9*64 = 73728
    float* wt_2   = wt_1 + 73728;          // 64*9*64  = 36864
    float* wt_3   = wt_2 + 36864;          // 64*9*32  = 18432
    float* wt_d   = wt_3 + 18432;          // 64*9*64  = 36864
    float* wt_r   = wt_d + 36864;          // 64*9*16  = 9216
    float* gap1   = wt_r + 9216;
    float* s1     = gap1 + 512;
    float* gap2   = s1 + 512;
    float* s2     = gap2 + 512;

    dim3 cgrid(12, 12, 8);

    k_wt<<<27, 256, 0, stream>>>(ref_w, wt_ref, 64, 64, 12);
    k_wt<<<288, 256, 0, stream>>>(off_w1, wt_1, 64, 64, 128);
    k_wt<<<144, 256, 0, stream>>>(off_w2, wt_2, 64, 64, 64);
    k_wt<<<72, 256, 0, stream>>>(off_w3, wt_3, 18, 32, 64);
    k_wt<<<144, 256, 0, stream>>>(dcn_w, wt_d, 64, 64, 64);
    k_wt<<<36, 256, 0, stream>>>(rgb_w, wt_r, 3, 16, 64);

    k_conv_ref<<<cgrid, 512, 0, stream>>>(ref_x, wt_ref, ref_b, bufA);
    k_conv_off1<<<cgrid, 512, 0, stream>>>(x, bufA, wt_1, off_b1, bufB);
    k_gap<<<512, 256, 0, stream>>>(bufB, gap1);
    k_cafc<<<8, 64, 0, stream>>>(gap1, ca1_w1, ca1_b1, ca1_w2, ca1_b2, s1);
    k_conv_off2<<<cgrid, 512, 0, stream>>>(bufB, wt_2, off_b2, s1, bufA);
    k_gap<<<512, 256, 0, stream>>>(bufA, gap2);
    k_cafc<<<8, 64, 0, stream>>>(gap2, ca2_w1, ca2_b1, ca2_w2, ca2_b2, s2);
    k_conv_off3<<<cgrid, 512, 0, stream>>>(bufA, wt_3, off_b3, s2, off_out, mask_out);
    k_dcn<<<cgrid, 256, 0, stream>>>(x, off_out, wt_d, dcn_b, xo_out);
    k_conv_rgb<<<cgrid, 512, 0, stream>>>(xo_out, wt_r, rgb_b, rgb_out);
}

// Round 4
// 458.621 us; speedup vs baseline: 13.3082x; 4.1610x over previous
//
#include <hip/hip_runtime.h>
#include <hip/hip_bf16.h>
#include <math.h>

#define HH 192
#define WW 192
#define HW (192*192)

typedef __attribute__((ext_vector_type(8))) short bfrag;   // 8 x bf16 (4 VGPR)
typedef __attribute__((ext_vector_type(4))) float ffrag;   // 4 x f32 acc

__device__ __forceinline__ float bf2f(ushort u){
    union { unsigned int i; float f; } c; c.i = ((unsigned int)u) << 16; return c.f;
}
__device__ __forceinline__ ushort f2bf(float f){
    __hip_bfloat16 h = __float2bfloat16(f);
    return *reinterpret_cast<ushort*>(&h);
}

// ---------------- NCHW f32 -> NHWC bf16 (64 ch), LDS-transposed, swizzled ----------------
__global__ __launch_bounds__(256)
void k_nhwc(const float* __restrict__ x, ushort* __restrict__ o){
    __shared__ ushort sT[256*64];
    const int n = blockIdx.y;
    const int px0 = blockIdx.x * 256;
    const int tid = threadIdx.x;
    for (int c = 0; c < 64; ++c){
        float v = x[((size_t)(n*64 + c))*HW + px0 + tid];
        int slot = (((c >> 3) ^ (tid & 7)) << 3) + (c & 7);
        sT[tid*64 + slot] = f2bf(v);
    }
    __syncthreads();
    for (int r = 0; r < 8; ++r){
        int u = r*256 + tid;
        int pl = u >> 3, g = u & 7;
        uint4 v = *(const uint4*)&sT[pl*64 + ((g ^ (pl & 7)) << 3)];
        *(uint4*)(o + ((size_t)n*HW + px0 + pl)*64 + g*8) = v;
    }
}

// ---------------- ref_x flip-augment -> NHWC bf16, 32 ch (12 real + 20 zero) ----------------
__global__ __launch_bounds__(256)
void k_refcat(const float* __restrict__ rx, ushort* __restrict__ o){
    const int n = blockIdx.y;
    const int px = blockIdx.x*256 + threadIdx.x;
    const int y = px / WW, x = px - y*WW;
    ushort v[32];
#pragma unroll
    for (int m = 0; m < 4; ++m){
        int ry = (m & 1) ? (HH-1-y) : y;
        int rxp = (m & 2) ? (WW-1-x) : x;
#pragma unroll
        for (int c = 0; c < 3; ++c)
            v[m*3+c] = f2bf(rx[((size_t)(n*3+c))*HW + ry*WW + rxp]);
    }
#pragma unroll
    for (int j = 12; j < 32; ++j) v[j] = 0;
#pragma unroll
    for (int k = 0; k < 4; ++k)
        *(uint4*)(o + ((size_t)n*HW + px)*32 + k*8) = *(uint4*)&v[k*8];
}

// ---------------- weights -> MFMA A-fragment order, bf16 ----------------
// layout: wf[cb][tap][mt][lane][e]; A[m][k]: m = lane&15 (cout), k = (lane>>4)*8+e (cin in chunk)
__global__ void k_wfrag(const float* __restrict__ w, ushort* __restrict__ wf,
                        int cin_real, int ncb, int cout_real, int mt){
    int idx = blockIdx.x*256 + threadIdx.x;
    int total = ncb*9*mt*512;
    if (idx >= total) return;
    int e = idx & 7;
    int lane = (idx >> 3) & 63;
    int rest = idx >> 9;
    int mtl = rest % mt;
    int tap = (rest / mt) % 9;
    int cb  = rest / (mt*9);
    int cout = mtl*16 + (lane & 15);
    int cin  = cb*32 + ((lane >> 4) << 3) + e;
    float v = 0.f;
    if (cout < cout_real && cin < cin_real)
        v = w[((size_t)cout*cin_real + cin)*9 + tap];
    wf[idx] = f2bf(v);
}

// ---------------- implicit-GEMM 3x3 conv via MFMA 16x16x32 bf16 ----------------
// block: 256 thr = 4 waves; output tile 16x16 px x MT*16 couts.
// wave wv owns rows 4wv..4wv+3; each wave computes MT m-frags x 4 n-frags.
// LDS: sXt[y18][x18][32cin] bf16, 8-ch groups XOR-swizzled (g ^ ((x>>1)&3)) -> 2-way banks (free).
// OM bit0: bf16 NHWC out (64ch); OM bit1: f32 NCHW out (dual if of1).
template<int NCB, int MT, bool SCALE, bool CONCAT, bool RELU, int OM>
__global__ __launch_bounds__(256, 2)
void k_conv(const ushort* __restrict__ in0, const ushort* __restrict__ in1,
            const ushort* __restrict__ wf, const float* __restrict__ bias,
            const float* __restrict__ scale,
            ushort* __restrict__ obf, float* __restrict__ of0, float* __restrict__ of1,
            int cout_real)
{
    __shared__ ushort sXt[18*18*32];
    const int tid = threadIdx.x;
    const int lane = tid & 63;
    const int wv = tid >> 6;
    const int n = blockIdx.z;
    const int ty0 = blockIdx.y*16, tx0 = blockIdx.x*16;
    const int lx = lane & 15;     // MFMA col -> px x
    const int lg = lane >> 4;     // MFMA k-group / row-group

    ffrag acc[MT][4];
#pragma unroll
    for (int mt = 0; mt < MT; ++mt)
#pragma unroll
        for (int q = 0; q < 4; ++q) acc[mt][q] = (ffrag){0.f,0.f,0.f,0.f};

    for (int cb = 0; cb < NCB; ++cb){
        __syncthreads();
        // stage 18x18 halo x 32 cin, f32-scale fused, bf16, swizzled
        for (int u = tid; u < 1296; u += 256){
            int yy = u / 72; int rr = u - yy*72; int xx = rr >> 2; int g = rr & 3;
            int gy = ty0 - 1 + yy, gx = tx0 - 1 + xx;
            uint4 val = make_uint4(0,0,0,0);
            if (gy >= 0 && gy < HH && gx >= 0 && gx < WW){
                const ushort* src; int ch; int stride;
                if constexpr (CONCAT){
                    src = (cb < 2) ? in0 : in1;
                    ch = (cb & 1)*32 + g*8;
                    stride = 64;
                } else {
                    src = in0; ch = cb*32 + g*8; stride = NCB*32;
                }
                val = *(const uint4*)(src + ((size_t)n*HW + gy*WW + gx)*stride + ch);
                if constexpr (SCALE){
                    ushort* e = (ushort*)&val;
                    int cb8 = cb*32 + g*8;
#pragma unroll
                    for (int j = 0; j < 8; ++j)
                        e[j] = f2bf(bf2f(e[j]) * scale[n*64 + cb8 + j]);
                }
            }
            *(uint4*)&sXt[((yy*18 + xx)*4 + (g ^ ((xx >> 1) & 3)))*8] = val;
        }
        __syncthreads();

        const bfrag* wbase = (const bfrag*)wf + (size_t)cb*9*MT*64 + lane;
        bfrag a[MT];
#pragma unroll
        for (int mt = 0; mt < MT; ++mt) a[mt] = wbase[mt*64];

#pragma unroll
        for (int tap = 0; tap < 9; ++tap){
            const int ky = tap / 3, kx = tap % 3;
            bfrag an[MT];
            if (tap < 8){
#pragma unroll
                for (int mt = 0; mt < MT; ++mt) an[mt] = wbase[(tap+1)*MT*64 + mt*64];
            }
#pragma unroll
            for (int q = 0; q < 4; ++q){
                const int yl = wv*4 + q + ky;
                const int xl = lx + kx;
                bfrag b = *(const bfrag*)&sXt[((yl*18 + xl)*4 + (lg ^ ((xl >> 1) & 3)))*8];
#pragma unroll
                for (int mt = 0; mt < MT; ++mt)
                    acc[mt][q] = __builtin_amdgcn_mfma_f32_16x16x32_bf16(a[mt], b, acc[mt][q], 0, 0, 0);
            }
            if (tap < 8){
#pragma unroll
                for (int mt = 0; mt < MT; ++mt) a[mt] = an[mt];
            }
        }
    }
    // epilogue: C/D layout col=lane&15 (px x), row=(lane>>4)*4+reg (cout)
    const int gx = tx0 + lx;
#pragma unroll
    for (int mt = 0; mt < MT; ++mt){
        const int co0 = mt*16 + lg*4;
#pragma unroll
        for (int q = 0; q < 4; ++q){
            const int gy = ty0 + wv*4 + q;
            float r[4];
#pragma unroll
            for (int j = 0; j < 4; ++j){
                float bv = (co0 + j < cout_real) ? bias[co0 + j] : 0.f;
                float v = acc[mt][q][j] + bv;
                if (RELU) v = fmaxf(v, 0.f);
                r[j] = v;
            }
            if constexpr (OM & 1){
                ushort pk[4];
#pragma unroll
                for (int j = 0; j < 4; ++j) pk[j] = f2bf(r[j]);
                *(uint2*)(obf + ((size_t)n*HW + gy*WW + gx)*64 + co0) = *(uint2*)pk;
            }
            if constexpr (OM & 2){
#pragma unroll
                for (int j = 0; j < 4; ++j){
                    int c = co0 + j;
                    if (c < cout_real){
                        size_t o = ((size_t)(n*cout_real + c))*HW + (size_t)gy*WW + gx;
                        of0[o] = r[j];
                        if (of1) of1[o] = r[j];
                    }
                }
            }
        }
    }
}

// ---------------- GAP partial: NHWC bf16 -> part[n][32][64] ----------------
__global__ __launch_bounds__(256)
void k_gap_part(const ushort* __restrict__ t, float* __restrict__ part){
    __shared__ float sR[32][64];
    const int n = blockIdx.y, sl = blockIdx.x;
    const int tid = threadIdx.x;
    const int pt = tid >> 3, g = tid & 7;
    float a[8] = {0,0,0,0,0,0,0,0};
    const int base = sl*1152;
    for (int it = 0; it < 36; ++it){
        int px = base + it*32 + pt;
        uint4 v = *(const uint4*)(t + ((size_t)n*HW + px)*64 + g*8);
        const ushort* e = (const ushort*)&v;
#pragma unroll
        for (int j = 0; j < 8; ++j) a[j] += bf2f(e[j]);
    }
#pragma unroll
    for (int j = 0; j < 8; ++j) sR[pt][g*8+j] = a[j];
    __syncthreads();
    if (tid < 64){
        float s = 0.f;
#pragma unroll
        for (int p = 0; p < 32; ++p) s += sR[p][tid];
        part[((size_t)n*32 + sl)*64 + tid] = s;
    }
}

// ---------------- channel-attention FC ----------------
__global__ void k_cafc(const float* __restrict__ part, const float* __restrict__ w1,
                       const float* __restrict__ b1, const float* __restrict__ w2,
                       const float* __restrict__ b2, float* __restrict__ s)
{
    int n = blockIdx.x;
    int c = threadIdx.x;  // 64
    __shared__ float y[64], z[4];
    float acc = 0.f;
    for (int sl = 0; sl < 32; ++sl) acc += part[((size_t)n*32 + sl)*64 + c];
    y[c] = acc * (1.f/(float)HW);
    __syncthreads();
    if (c < 4){
        float a = b1[c];
        for (int i = 0; i < 64; ++i) a = fmaf(w1[c*64+i], y[i], a);
        z[c] = fmaxf(a, 0.f);
    }
    __syncthreads();
    float a = b2[c];
#pragma unroll
    for (int q = 0; q < 4; ++q) a = fmaf(w2[c*4+q], z[q], a);
    s[n*64+c] = 1.f/(1.f+expf(-a));
}

// ---------------- deformable conv: global bf16 NHWC gather -> bilinear -> MFMA ----------------
__global__ __launch_bounds__(256, 2)
void k_dcnm(const ushort* __restrict__ xbf, const float* __restrict__ off,
            const ushort* __restrict__ wf, const float* __restrict__ bias,
            float* __restrict__ xo, ushort* __restrict__ xobf)
{
    const int tid = threadIdx.x;
    const int lane = tid & 63;
    const int wv = tid >> 6;
    const int n = blockIdx.z;
    const int ty0 = blockIdx.y*16, tx0 = blockIdx.x*16;
    const int lx = lane & 15;
    const int lg = lane >> 4;
    const int gx = tx0 + lx;

    const ushort* xn = xbf + (size_t)n*HW*64;

    ffrag acc[4][4];
#pragma unroll
    for (int mt = 0; mt < 4; ++mt)
#pragma unroll
        for (int q = 0; q < 4; ++q) acc[mt][q] = (ffrag){0.f,0.f,0.f,0.f};

#pragma unroll
    for (int tap = 0; tap < 9; ++tap){
        const int ti = tap/3, tj = tap%3;
        float w00[4], w01[4], w10[4], w11[4];
        int a00[4], a01[4], a10[4], a11[4];
#pragma unroll
        for (int q = 0; q < 4; ++q){
            const int gy = ty0 + wv*4 + q;
            float dy = off[((size_t)(n*18 + 2*tap))*HW + gy*WW + gx];
            float dx = off[((size_t)(n*18 + 2*tap + 1))*HW + gy*WW + gx];
            float py = (float)(gy + ti - 1) + dy;
            float px = (float)(gx + tj - 1) + dx;
            float y0f = floorf(py), x0f = floorf(px);
            float wy1 = py - y0f, wx1 = px - x0f;
            float wy0 = 1.f - wy1, wx0 = 1.f - wx1;
            int y0 = (int)y0f, x0 = (int)x0f;
            int y1 = y0+1, x1 = x0+1;
            float vy0 = (y0 >= 0 && y0 < HH) ? 1.f : 0.f;
            float vy1 = (y1 >= 0 && y1 < HH) ? 1.f : 0.f;
            float vx0 = (x0 >= 0 && x0 < WW) ? 1.f : 0.f;
            float vx1 = (x1 >= 0 && x1 < WW) ? 1.f : 0.f;
            w00[q] = wy0*wx0*vy0*vx0; w01[q] = wy0*wx1*vy0*vx1;
            w10[q] = wy1*wx0*vy1*vx0; w11[q] = wy1*wx1*vy1*vx1;
            int yc0 = min(max(y0,0),HH-1), yc1 = min(max(y1,0),HH-1);
            int xc0 = min(max(x0,0),WW-1), xc1 = min(max(x1,0),WW-1);
            a00[q] = (yc0*WW + xc0)*64; a01[q] = (yc0*WW + xc1)*64;
            a10[q] = (yc1*WW + xc0)*64; a11[q] = (yc1*WW + xc1)*64;
        }
#pragma unroll
        for (int cb = 0; cb < 2; ++cb){
            const bfrag* wbase = (const bfrag*)wf + ((size_t)(cb*9 + tap)*4)*64 + lane;
            bfrag a[4];
#pragma unroll
            for (int mt = 0; mt < 4; ++mt) a[mt] = wbase[mt*64];
            const int cg = cb*32 + lg*8;
#pragma unroll
            for (int q = 0; q < 4; ++q){
                uint4 c00 = *(const uint4*)(xn + a00[q] + cg);
                uint4 c01 = *(const uint4*)(xn + a01[q] + cg);
                uint4 c10 = *(const uint4*)(xn + a10[q] + cg);
                uint4 c11 = *(const uint4*)(xn + a11[q] + cg);
                const ushort* e00 = (const ushort*)&c00;
                const ushort* e01 = (const ushort*)&c01;
                const ushort* e10 = (const ushort*)&c10;
                const ushort* e11 = (const ushort*)&c11;
                ushort pk[8];
#pragma unroll
                for (int j = 0; j < 8; ++j){
                    float s = bf2f(e00[j])*w00[q] + bf2f(e01[j])*w01[q]
                            + bf2f(e10[j])*w10[q] + bf2f(e11[j])*w11[q];
                    pk[j] = f2bf(s);
                }
                bfrag b = *(bfrag*)pk;
#pragma unroll
                for (int mt = 0; mt < 4; ++mt)
                    acc[mt][q] = __builtin_amdgcn_mfma_f32_16x16x32_bf16(a[mt], b, acc[mt][q], 0, 0, 0);
            }
        }
    }
    // epilogue: relu(acc+bias) -> xo f32 NCHW + xobf bf16 NHWC
#pragma unroll
    for (int mt = 0; mt < 4; ++mt){
        const int co0 = mt*16 + lg*4;
#pragma unroll
        for (int q = 0; q < 4; ++q){
            const int gy = ty0 + wv*4 + q;
            float r[4];
            ushort pk[4];
#pragma unroll
            for (int j = 0; j < 4; ++j){
                r[j] = fmaxf(acc[mt][q][j] + bias[co0+j], 0.f);
                pk[j] = f2bf(r[j]);
            }
#pragma unroll
            for (int j = 0; j < 4; ++j)
                xo[((size_t)(n*64 + co0 + j))*HW + (size_t)gy*WW + gx] = r[j];
            *(uint2*)(xobf + ((size_t)n*HW + gy*WW + gx)*64 + co0) = *(uint2*)pk;
        }
    }
}

extern "C" void kernel_launch(void* const* d_in, const int* in_sizes, int n_in,
                              void* d_out, int out_size, void* d_ws, size_t ws_size,
                              hipStream_t stream)
{
    const float* x      = (const float*)d_in[0];
    const float* ref_x  = (const float*)d_in[1];
    const float* ref_w  = (const float*)d_in[2];
    const float* ref_b  = (const float*)d_in[3];
    const float* off_w1 = (const float*)d_in[4];
    const float* off_b1 = (const float*)d_in[5];
    const float* ca1_w1 = (const float*)d_in[6];
    const float* ca1_b1 = (const float*)d_in[7];
    const float* ca1_w2 = (const float*)d_in[8];
    const float* ca1_b2 = (const float*)d_in[9];
    const float* off_w2 = (const float*)d_in[10];
    const float* off_b2 = (const float*)d_in[11];
    const float* ca2_w1 = (const float*)d_in[12];
    const float* ca2_b1 = (const float*)d_in[13];
    const float* ca2_w2 = (const float*)d_in[14];
    const float* ca2_b2 = (const float*)d_in[15];
    const float* off_w3 = (const float*)d_in[16];
    const float* off_b3 = (const float*)d_in[17];
    const float* dcn_w  = (const float*)d_in[18];
    const float* dcn_b  = (const float*)d_in[19];
    const float* rgb_w  = (const float*)d_in[20];
    const float* rgb_b  = (const float*)d_in[21];

    float* out = (float*)d_out;
    const size_t XO  = (size_t)8 * 64 * HW;
    const size_t RGB = (size_t)8 * 3 * HW;
    const size_t OFF = (size_t)8 * 18 * HW;
    float* xo_out   = out;
    float* rgb_out  = out + XO;
    float* mask_out = out + XO + RGB;
    float* off_out  = out + XO + RGB + OFF;

    const size_t NPX = (size_t)8 * HW;   // 294912
    ushort* ws16  = (ushort*)d_ws;
    ushort* x_bf  = ws16;                       // NPX*64
    ushort* bufP  = x_bf + NPX*64;              // ref_f, later t2
    ushort* bufQ  = bufP + NPX*64;              // t1, later xo_bf
    ushort* rc_bf = bufQ + NPX*64;              // NPX*32
    ushort* wf_ref = rc_bf + NPX*32;            // 1*9*4*512 = 18432
    ushort* wf_1   = wf_ref + 18432;            // 4*9*4*512 = 73728
    ushort* wf_2   = wf_1 + 73728;              // 2*9*4*512 = 36864
    ushort* wf_3   = wf_2 + 36864;              // 2*9*2*512 = 18432
    ushort* wf_d   = wf_3 + 18432;              // 36864
    ushort* wf_r   = wf_d + 36864;              // 2*9*1*512 = 9216
    float*  part1  = (float*)(wf_r + 9216);     // 8*32*64
    float*  part2  = part1 + 16384;
    float*  s1     = part2 + 16384;
    float*  s2     = s1 + 512;

    dim3 pg(144, 8), cg(12, 12, 8);

    k_nhwc<<<pg, 256, 0, stream>>>(x, x_bf);
    k_refcat<<<pg, 256, 0, stream>>>(ref_x, rc_bf);
    k_wfrag<<<72, 256, 0, stream>>>(ref_w, wf_ref, 12, 1, 64, 4);
    k_wfrag<<<288, 256, 0, stream>>>(off_w1, wf_1, 128, 4, 64, 4);
    k_wfrag<<<144, 256, 0, stream>>>(off_w2, wf_2, 64, 2, 64, 4);
    k_wfrag<<<72, 256, 0, stream>>>(off_w3, wf_3, 64, 2, 18, 2);
    k_wfrag<<<144, 256, 0, stream>>>(dcn_w, wf_d, 64, 2, 64, 4);
    k_wfrag<<<36, 256, 0, stream>>>(rgb_w, wf_r, 64, 2, 3, 1);

    // ref: 32ch(12 real) -> 64, relu, bf16 out
    k_conv<1,4,false,false,true,1><<<cg, 256, 0, stream>>>(
        rc_bf, nullptr, wf_ref, ref_b, nullptr, bufP, nullptr, nullptr, 64);
    // off1: concat(x, ref_f) 128 -> 64, relu, bf16 out
    k_conv<4,4,false,true,true,1><<<cg, 256, 0, stream>>>(
        x_bf, bufP, wf_1, off_b1, nullptr, bufQ, nullptr, nullptr, 64);
    k_gap_part<<<dim3(32,8), 256, 0, stream>>>(bufQ, part1);
    k_cafc<<<8, 64, 0, stream>>>(part1, ca1_w1, ca1_b1, ca1_w2, ca1_b2, s1);
    // off2: (t1*s1) 64 -> 64, relu, bf16 out
    k_conv<2,4,true,false,true,1><<<cg, 256, 0, stream>>>(
        bufQ, nullptr, wf_2, off_b2, s1, bufP, nullptr, nullptr, 64);
    k_gap_part<<<dim3(32,8), 256, 0, stream>>>(bufP, part2);
    k_cafc<<<8, 64, 0, stream>>>(part2, ca2_w1, ca2_b1, ca2_w2, ca2_b2, s2);
    // off3: (t2*s2) 64 -> 18, f32 NCHW dual (offset + mask)
    k_conv<2,2,true,false,false,2><<<cg, 256, 0, stream>>>(
        bufP, nullptr, wf_3, off_b3, s2, nullptr, off_out, mask_out, 18);
    // deformable conv -> xo (f32 NCHW) + xo_bf (NHWC)
    k_dcnm<<<cg, 256, 0, stream>>>(x_bf, off_out, wf_d, dcn_b, xo_out, bufQ);
    // rgb: xo 64 -> 3, f32 NCHW
    k_conv<2,1,false,false,false,2><<<cg, 256, 0, stream>>>(
        bufQ, nullptr, wf_r, rgb_b, nullptr, nullptr, rgb_out, nullptr, 3);
}